// Round 1
// baseline (25872.638 us; speedup 1.0000x reference)
//
#include <hip/hip_runtime.h>
#include <hip/hip_fp16.h>

#define B_ 256
#define S_ 512
#define F_ 64
#define H_ 1024
#define O_ 24
#define G_ 4096  // 4*H

typedef _Float16 half_t;
typedef _Float16 h8 __attribute__((ext_vector_type(8)));
typedef float f4 __attribute__((ext_vector_type(4)));

// ---- workspace layout (bytes) ----
// zeroed region first:
#define OFF_H1 ((size_t)0)                                   // 2*B*H halfs (ping-pong)
#define OFF_H2 (OFF_H1 + (size_t)2*B_*H_*2)
#define OFF_C1 (OFF_H2 + (size_t)2*B_*H_*2)                  // B*H f32
#define OFF_C2 (OFF_C1 + (size_t)B_*H_*4)
#define OFF_OP (OFF_C2 + (size_t)B_*H_*4)                    // out_part [32][B][O] f32
#define ZBYTES (OFF_OP + (size_t)32*B_*O_*4)
// non-zeroed (overwritten every launch):
#define OFF_BIAS0 (ZBYTES)
#define OFF_BIAS1 (OFF_BIAS0 + (size_t)G_*4)
#define OFF_XH    (OFF_BIAS1 + (size_t)G_*4)                 // B*S*F halfs
#define OFF_WIH0  (OFF_XH + (size_t)B_*S_*F_*2)              // G*F halfs
#define OFF_WHH0  (OFF_WIH0 + (size_t)G_*F_*2)               // G*H halfs
#define OFF_WIH1  (OFF_WHH0 + (size_t)G_*H_*2)
#define OFF_WHH1  (OFF_WIH1 + (size_t)G_*H_*2)
#define WS_NEEDED (OFF_WHH1 + (size_t)G_*H_*2)               // ~47.5 MB

__global__ void k_bias(const float* __restrict__ bi0, const float* __restrict__ bh0,
                       const float* __restrict__ bi1, const float* __restrict__ bh1,
                       float* __restrict__ bias0, float* __restrict__ bias1) {
    int i = blockIdx.x * blockDim.x + threadIdx.x;
    if (i < G_) { bias0[i] = bi0[i] + bh0[i]; bias1[i] = bi1[i] + bh1[i]; }
}

__global__ void k_cvt(const float* __restrict__ src, half_t* __restrict__ dst, int n) {
    int i = blockIdx.x * blockDim.x + threadIdx.x;
    int stride = gridDim.x * blockDim.x;
    for (; i < n; i += stride) dst[i] = (half_t)src[i];
}

// One LSTM layer step. Block tile: 32 batch rows x 32 h-cols x 4 gates.
// Grid: (B/32=8, H/32=32) = 256 blocks, 256 threads = 4 waves, wave w owns gate w.
// gates = xin @ Wih^T + hprev @ Whh^T + bias; cell; write hnext (fp16), c (fp32, in-place).
// HAS_FC: also accumulate out_part[ht][b][o] += h * fcW[o][t*H + h] (fp32).
template<bool HAS_FC>
__global__ __launch_bounds__(256)
void k_step(const half_t* __restrict__ xbase, int ldx, int cx,
            const half_t* __restrict__ Wih, int ldwih,
            const half_t* __restrict__ hprev,
            const half_t* __restrict__ Whh,
            const float* __restrict__ bias,
            float* __restrict__ c,
            half_t* __restrict__ hnext,
            const float* __restrict__ fcWt,
            float* __restrict__ out_part)
{
    __shared__ half_t A_s[32 * 72];     // 32 rows x 64 k, stride 72 (144B, 16B-aligned, conflict-benign)
    __shared__ half_t W_s[128 * 72];    // 4 gates x 32 rows x 64 k
    __shared__ float gate_s[4][32 * 33];
    __shared__ float h_s[32 * 33];

    const int thr  = threadIdx.x;
    const int wave = thr >> 6, lane = thr & 63;
    const int quad = lane >> 4, l15 = lane & 15;
    const int bt = blockIdx.x, ht = blockIdx.y;

    f4 acc[2][2] = {};

    const int nchunks = cx + 16;            // K = cx*64 (input) + 1024 (hidden)
    const int ar = thr >> 3;                // A staging: row 0..31
    const int ak = (thr & 7) * 8;           // k offset 0..56

    for (int ck = 0; ck < nchunks; ++ck) {
        const half_t* Ab; int lda, k0; const half_t* Wb; int ldw;
        if (ck < cx) { Ab = xbase; lda = ldx;  k0 = ck * 64;        Wb = Wih; ldw = ldwih; }
        else         { Ab = hprev; lda = H_;   k0 = (ck - cx) * 64; Wb = Whh; ldw = H_;    }

        // stage A tile (32x64 halfs): 16B per thread
        *(f4*)&A_s[ar * 72 + ak] = *(const f4*)&Ab[(size_t)(bt * 32 + ar) * lda + k0 + ak];
        // stage W tile (128x64 halfs): 4x16B per thread
        #pragma unroll
        for (int j = 0; j < 4; ++j) {
            int idx = thr + 256 * j;
            int r = idx >> 3, kk = (idx & 7) * 8;
            int q = r >> 5, rr = r & 31;
            *(f4*)&W_s[r * 72 + kk] =
                *(const f4*)&Wb[(size_t)(q * H_ + ht * 32 + rr) * ldw + k0 + kk];
        }
        __syncthreads();

        #pragma unroll
        for (int ks = 0; ks < 64; ks += 32) {
            // A-frag: lane holds A[m=l15][k = ks + quad*8 + j], j=0..7 (16B contiguous)
            h8 a0 = *(const h8*)&A_s[(0  + l15) * 72 + ks + quad * 8];
            h8 a1 = *(const h8*)&A_s[(16 + l15) * 72 + ks + quad * 8];
            // B-frag: lane holds W[n=l15][k...] == B[k][n] for gates = A @ W^T
            h8 b0 = *(const h8*)&W_s[(wave * 32 + 0  + l15) * 72 + ks + quad * 8];
            h8 b1 = *(const h8*)&W_s[(wave * 32 + 16 + l15) * 72 + ks + quad * 8];
            acc[0][0] = __builtin_amdgcn_mfma_f32_16x16x32_f16(a0, b0, acc[0][0], 0, 0, 0);
            acc[0][1] = __builtin_amdgcn_mfma_f32_16x16x32_f16(a0, b1, acc[0][1], 0, 0, 0);
            acc[1][0] = __builtin_amdgcn_mfma_f32_16x16x32_f16(a1, b0, acc[1][0], 0, 0, 0);
            acc[1][1] = __builtin_amdgcn_mfma_f32_16x16x32_f16(a1, b1, acc[1][1], 0, 0, 0);
        }
        __syncthreads();
    }

    // scatter gates to LDS: C/D layout col=lane&15, row=quad*4+reg (m89-verified)
    #pragma unroll
    for (int mt = 0; mt < 2; ++mt)
        #pragma unroll
        for (int nt = 0; nt < 2; ++nt)
            #pragma unroll
            for (int r = 0; r < 4; ++r)
                gate_s[wave][(mt * 16 + quad * 4 + r) * 33 + nt * 16 + l15] = acc[mt][nt][r];
    __syncthreads();

    // cell: 1024 (b,h) elements, 4 per thread
    const int hbase = ht * 32;
    #pragma unroll
    for (int kk = 0; kk < 4; ++kk) {
        int e = thr + kk * 256;
        int b = e >> 5, col = e & 31;
        float gi = gate_s[0][b * 33 + col] + bias[0 * H_ + hbase + col];
        float gf = gate_s[1][b * 33 + col] + bias[1 * H_ + hbase + col];
        float gg = gate_s[2][b * 33 + col] + bias[2 * H_ + hbase + col];
        float go = gate_s[3][b * 33 + col] + bias[3 * H_ + hbase + col];
        float si = 1.f / (1.f + __expf(-gi));
        float sf = 1.f / (1.f + __expf(-gf));
        float so = 1.f / (1.f + __expf(-go));
        float tg = tanhf(gg);
        size_t cidx = (size_t)(bt * 32 + b) * H_ + hbase + col;
        float cn = sf * c[cidx] + si * tg;
        c[cidx] = cn;
        float hn = so * tanhf(cn);
        hnext[cidx] = (half_t)hn;
        h_s[b * 33 + col] = hn;
    }

    if (HAS_FC) {
        __syncthreads();
        // out_part[ht][bt*32+bb][o] += sum_j h[bb][j] * fcW[o][t*H + hbase + j]
        for (int p = thr; p < 32 * O_; p += 256) {
            int o = p >> 5, bb = p & 31;
            float s = 0.f;
            #pragma unroll 8
            for (int j = 0; j < 32; ++j)
                s += h_s[bb * 33 + j] * fcWt[(size_t)o * (S_ * H_) + hbase + j];
            out_part[ht * (B_ * O_) + (bt * 32 + bb) * O_ + o] += s;
        }
    }
}

__global__ void k_final(const float* __restrict__ out_part, const float* __restrict__ fcb,
                        float* __restrict__ out) {
    int i = blockIdx.x * blockDim.x + threadIdx.x;
    if (i >= B_ * O_) return;
    int o = i % O_;
    float s = fcb[o];
    for (int t = 0; t < 32; ++t) s += out_part[t * (B_ * O_) + i];
    out[i] = s;
}

extern "C" void kernel_launch(void* const* d_in, const int* in_sizes, int n_in,
                              void* d_out, int out_size, void* d_ws, size_t ws_size,
                              hipStream_t stream) {
    const float* x    = (const float*)d_in[0];
    const float* Wih0 = (const float*)d_in[1];
    const float* Whh0 = (const float*)d_in[2];
    const float* bih0 = (const float*)d_in[3];
    const float* bhh0 = (const float*)d_in[4];
    const float* Wih1 = (const float*)d_in[5];
    const float* Whh1 = (const float*)d_in[6];
    const float* bih1 = (const float*)d_in[7];
    const float* bhh1 = (const float*)d_in[8];
    const float* fcW  = (const float*)d_in[9];
    const float* fcb  = (const float*)d_in[10];

    char* ws = (char*)d_ws;
    half_t* h1buf  = (half_t*)(ws + OFF_H1);
    half_t* h2buf  = (half_t*)(ws + OFF_H2);
    float*  c1     = (float*)(ws + OFF_C1);
    float*  c2     = (float*)(ws + OFF_C2);
    float*  opart  = (float*)(ws + OFF_OP);
    float*  bias0  = (float*)(ws + OFF_BIAS0);
    float*  bias1  = (float*)(ws + OFF_BIAS1);
    half_t* x_h    = (half_t*)(ws + OFF_XH);
    half_t* wih0_h = (half_t*)(ws + OFF_WIH0);
    half_t* whh0_h = (half_t*)(ws + OFF_WHH0);
    half_t* wih1_h = (half_t*)(ws + OFF_WIH1);
    half_t* whh1_h = (half_t*)(ws + OFF_WHH1);

    // zero states + FC partials (ws is poisoned 0xAA before every launch)
    hipMemsetAsync(d_ws, 0, ZBYTES, stream);

    k_bias<<<dim3((G_ + 255) / 256), dim3(256), 0, stream>>>(bih0, bhh0, bih1, bhh1, bias0, bias1);
    k_cvt<<<dim3(2048), dim3(256), 0, stream>>>(x,    x_h,    B_ * S_ * F_);
    k_cvt<<<dim3(256),  dim3(256), 0, stream>>>(Wih0, wih0_h, G_ * F_);
    k_cvt<<<dim3(2048), dim3(256), 0, stream>>>(Whh0, whh0_h, G_ * H_);
    k_cvt<<<dim3(2048), dim3(256), 0, stream>>>(Wih1, wih1_h, G_ * H_);
    k_cvt<<<dim3(2048), dim3(256), 0, stream>>>(Whh1, whh1_h, G_ * H_);

    dim3 grid(B_ / 32, H_ / 32), blk(256);
    for (int t = 0; t < S_; ++t) {
        int p = t & 1;
        half_t* h1p = h1buf + (size_t)p * B_ * H_;
        half_t* h1n = h1buf + (size_t)(1 - p) * B_ * H_;
        half_t* h2p = h2buf + (size_t)p * B_ * H_;
        half_t* h2n = h2buf + (size_t)(1 - p) * B_ * H_;
        // layer 0: input = x[:, t, :] (fp16), K_x = 64 (1 chunk)
        k_step<false><<<grid, blk, 0, stream>>>(x_h + (size_t)t * F_, S_ * F_, 1,
                                                wih0_h, F_, h1p, whh0_h, bias0,
                                                c1, h1n, nullptr, nullptr);
        // layer 1: input = h1[t] (just written), K_x = 1024 (16 chunks) + FC partial
        k_step<true><<<grid, blk, 0, stream>>>(h1n, H_, 16,
                                               wih1_h, H_, h2p, whh1_h, bias1,
                                               c2, h2n, fcW + (size_t)t * H_, opart);
    }
    k_final<<<dim3((B_ * O_ + 255) / 256), dim3(256), 0, stream>>>(opart, fcb, (float*)d_out);
}

// Round 2
// 12816.260 us; speedup vs baseline: 2.0187x; 2.0187x over previous
//
#include <hip/hip_runtime.h>
#include <hip/hip_fp16.h>

#define B_ 256
#define S_ 512
#define F_ 64
#define H_ 1024
#define O_ 24
#define G_ 4096  // 4*H

typedef _Float16 half_t;
typedef _Float16 h8 __attribute__((ext_vector_type(8)));
typedef float f4 __attribute__((ext_vector_type(4)));

// ---- workspace layout (bytes) ----
// zeroed region first:
#define OFF_H1 ((size_t)0)                                   // 2*B*H halfs (ping-pong)
#define OFF_H2 (OFF_H1 + (size_t)2*B_*H_*2)
#define OFF_C1 (OFF_H2 + (size_t)2*B_*H_*2)                  // B*H f32
#define OFF_C2 (OFF_C1 + (size_t)B_*H_*4)
#define OFF_OP (OFF_C2 + (size_t)B_*H_*4)                    // out_part [32][B][O] f32
#define ZBYTES (OFF_OP + (size_t)32*B_*O_*4)
// non-zeroed (overwritten every launch):
#define OFF_BIAS0 (ZBYTES)
#define OFF_BIAS1 (OFF_BIAS0 + (size_t)G_*4)
#define OFF_XH    (OFF_BIAS1 + (size_t)G_*4)                 // B*S*F halfs
#define OFF_WIH0  (OFF_XH + (size_t)B_*S_*F_*2)              // G*F halfs
#define OFF_WHH0  (OFF_WIH0 + (size_t)G_*F_*2)               // G*H halfs
#define OFF_WIH1  (OFF_WHH0 + (size_t)G_*H_*2)
#define OFF_WHH1  (OFF_WIH1 + (size_t)G_*H_*2)
#define WS_NEEDED (OFF_WHH1 + (size_t)G_*H_*2)               // ~47.5 MB

__global__ void k_bias(const float* __restrict__ bi0, const float* __restrict__ bh0,
                       const float* __restrict__ bi1, const float* __restrict__ bh1,
                       float* __restrict__ bias0, float* __restrict__ bias1) {
    int i = blockIdx.x * blockDim.x + threadIdx.x;
    if (i < G_) { bias0[i] = bi0[i] + bh0[i]; bias1[i] = bi1[i] + bh1[i]; }
}

__global__ void k_cvt(const float* __restrict__ src, half_t* __restrict__ dst, int n) {
    int i = blockIdx.x * blockDim.x + threadIdx.x;
    int stride = gridDim.x * blockDim.x;
    for (; i < n; i += stride) dst[i] = (half_t)src[i];
}

// Fused phase kernel. Phase t runs layer0 step t (blocks 256..511) and
// layer1 step t-1 (blocks 0..255) concurrently — independent work, so one
// launch per phase, 2 blocks/CU (one per layer) for stall overlap.
// Block tile: 32 batch x 32 h x 4 gates; 4 waves, wave w = gate w.
// Block->(ht,bt) mapping keeps ht%8 == linear_id%8 so each XCD (id%8) sees
// only 4 ht weight slices (~3 MB) -> weights stay L2-resident across steps.
__global__ __launch_bounds__(256, 2)
void k_phase(int t,
             const half_t* __restrict__ x_h,
             const half_t* __restrict__ Wih0, const half_t* __restrict__ Whh0,
             const float* __restrict__ bias0, float* __restrict__ c1, half_t* __restrict__ h1buf,
             const half_t* __restrict__ Wih1, const half_t* __restrict__ Whh1,
             const float* __restrict__ bias1, float* __restrict__ c2, half_t* __restrict__ h2buf,
             const float* __restrict__ fcW, float* __restrict__ out_part)
{
    // staging LDS unioned with gate-exchange LDS (both <= 23040 B)
    __shared__ __align__(16) char smraw[23040];
    half_t* A_s    = (half_t*)smraw;                     // 32 x 72  (stride 72: 2-way bank alias = free)
    half_t* W_s    = (half_t*)(smraw + 32 * 72 * 2);     // 128 x 72
    float*  gate_s = (float*)smraw;                      // [4][32*33]
    float*  h_s    = (float*)(smraw + 4 * 32 * 33 * 4);  // [32*33]

    const int n  = blockIdx.x;
    const bool l1 = (n < 256);
    const int m  = l1 ? n : n - 256;
    const int ht = (m & 7) + 8 * ((m >> 3) & 3);   // ht % 8 == linear_id % 8
    const int bt = (m >> 5) & 7;

    int tt; const half_t* xb; int ldx, cx; const half_t* Wih; int ldwih;
    const half_t* Whh; const float* bias; float* c; half_t* hn_out; const half_t* hp;
    if (l1) {
        if (t == 0) return;
        tt = t - 1;
        xb  = h1buf + (size_t)(tt & 1) * B_ * H_;  ldx = H_;      cx = 16;
        Wih = Wih1;  ldwih = H_;  Whh = Whh1;  bias = bias1;  c = c2;
        hp     = h2buf + (size_t)((tt - 1) & 1) * B_ * H_;
        hn_out = h2buf + (size_t)(tt & 1) * B_ * H_;
    } else {
        if (t >= S_) return;
        tt = t;
        xb  = x_h + (size_t)tt * F_;  ldx = S_ * F_;  cx = 1;
        Wih = Wih0;  ldwih = F_;  Whh = Whh0;  bias = bias0;  c = c1;
        hp     = h1buf + (size_t)((tt - 1) & 1) * B_ * H_;
        hn_out = h1buf + (size_t)(tt & 1) * B_ * H_;
    }

    const int thr  = threadIdx.x;
    const int wave = thr >> 6, lane = thr & 63;
    const int quad = lane >> 4, l15 = lane & 15;
    const int hbase = ht * 32;

    // fold bias (b_ih+b_hh) into accumulator init: acc elem (row=batch,col=h),
    // col = nt*16 + l15, same for all rows/regs.
    float bv0 = bias[wave * H_ + hbase + l15];
    float bv1 = bias[wave * H_ + hbase + 16 + l15];
    f4 acc[2][2];
    #pragma unroll
    for (int mt = 0; mt < 2; ++mt) {
        acc[mt][0] = (f4){bv0, bv0, bv0, bv0};
        acc[mt][1] = (f4){bv1, bv1, bv1, bv1};
    }

    const int nchunks = cx + 16;            // K = cx*64 (input) + 1024 (hidden)
    const int ar = thr >> 3;                // A staging row 0..31
    const int ak = (thr & 7) * 8;           // k offset 0..56

    int Wr[4], Wk[4];
    #pragma unroll
    for (int j = 0; j < 4; ++j) { int idx = thr + 256 * j; Wr[j] = idx >> 3; Wk[j] = (idx & 7) * 8; }

    // VGPR prefetch double-buffer: fetch chunk ck+1 while MFMAing chunk ck
    f4 pA; f4 pW[4];
    auto fetch = [&](int ck) {
        const half_t* Ab; int lda, k0; const half_t* Wb; int ldw;
        if (ck < cx) { Ab = xb; lda = ldx;  k0 = ck * 64;        Wb = Wih; ldw = ldwih; }
        else         { Ab = hp; lda = H_;   k0 = (ck - cx) * 64; Wb = Whh; ldw = H_;    }
        pA = *(const f4*)&Ab[(size_t)(bt * 32 + ar) * lda + k0 + ak];
        #pragma unroll
        for (int j = 0; j < 4; ++j) {
            int r = Wr[j], q = r >> 5, rr = r & 31;
            pW[j] = *(const f4*)&Wb[(size_t)(q * H_ + hbase + rr) * ldw + k0 + Wk[j]];
        }
    };

    fetch(0);
    for (int ck = 0; ck < nchunks; ++ck) {
        *(f4*)&A_s[ar * 72 + ak] = pA;
        #pragma unroll
        for (int j = 0; j < 4; ++j) *(f4*)&W_s[Wr[j] * 72 + Wk[j]] = pW[j];
        __syncthreads();
        if (ck + 1 < nchunks) fetch(ck + 1);   // loads fly during MFMA below

        #pragma unroll
        for (int ks = 0; ks < 64; ks += 32) {
            h8 a0 = *(const h8*)&A_s[(0  + l15) * 72 + ks + quad * 8];
            h8 a1 = *(const h8*)&A_s[(16 + l15) * 72 + ks + quad * 8];
            h8 b0 = *(const h8*)&W_s[(wave * 32 + 0  + l15) * 72 + ks + quad * 8];
            h8 b1 = *(const h8*)&W_s[(wave * 32 + 16 + l15) * 72 + ks + quad * 8];
            acc[0][0] = __builtin_amdgcn_mfma_f32_16x16x32_f16(a0, b0, acc[0][0], 0, 0, 0);
            acc[0][1] = __builtin_amdgcn_mfma_f32_16x16x32_f16(a0, b1, acc[0][1], 0, 0, 0);
            acc[1][0] = __builtin_amdgcn_mfma_f32_16x16x32_f16(a1, b0, acc[1][0], 0, 0, 0);
            acc[1][1] = __builtin_amdgcn_mfma_f32_16x16x32_f16(a1, b1, acc[1][1], 0, 0, 0);
        }
        __syncthreads();
    }

    // scatter gates (C/D layout col=lane&15, row=quad*4+reg) — smraw reuse is
    // safe: the loop-final barrier drained all ds_reads.
    #pragma unroll
    for (int mt = 0; mt < 2; ++mt)
        #pragma unroll
        for (int nt = 0; nt < 2; ++nt)
            #pragma unroll
            for (int r = 0; r < 4; ++r)
                gate_s[wave * (32 * 33) + (mt * 16 + quad * 4 + r) * 33 + nt * 16 + l15] = acc[mt][nt][r];
    __syncthreads();

    // cell update: 1024 (b,h) elems, 4/thread; bias already in gates
    #pragma unroll
    for (int kk = 0; kk < 4; ++kk) {
        int e = thr + kk * 256;
        int b = e >> 5, col = e & 31;
        float gi = gate_s[0 * (32 * 33) + b * 33 + col];
        float gf = gate_s[1 * (32 * 33) + b * 33 + col];
        float gg = gate_s[2 * (32 * 33) + b * 33 + col];
        float go = gate_s[3 * (32 * 33) + b * 33 + col];
        float si = 1.f / (1.f + __expf(-gi));
        float sf = 1.f / (1.f + __expf(-gf));
        float so = 1.f / (1.f + __expf(-go));
        float tg = tanhf(gg);
        size_t cidx = (size_t)(bt * 32 + b) * H_ + hbase + col;
        float cn = sf * c[cidx] + si * tg;
        c[cidx] = cn;
        float hnv = so * tanhf(cn);
        hn_out[cidx] = (half_t)hnv;
        h_s[b * 33 + col] = hnv;
    }

    if (l1) {
        __syncthreads();
        const float* fcWt = fcW + (size_t)tt * H_;
        for (int p = thr; p < 32 * O_; p += 256) {
            int o = p >> 5, bb = p & 31;
            float s = 0.f;
            #pragma unroll 8
            for (int j = 0; j < 32; ++j)
                s += h_s[bb * 33 + j] * fcWt[(size_t)o * (S_ * H_) + hbase + j];
            out_part[ht * (B_ * O_) + (bt * 32 + bb) * O_ + o] += s;
        }
    }
}

__global__ void k_final(const float* __restrict__ out_part, const float* __restrict__ fcb,
                        float* __restrict__ out) {
    int i = blockIdx.x * blockDim.x + threadIdx.x;
    if (i >= B_ * O_) return;
    int o = i % O_;
    float s = fcb[o];
    for (int t = 0; t < 32; ++t) s += out_part[t * (B_ * O_) + i];
    out[i] = s;
}

extern "C" void kernel_launch(void* const* d_in, const int* in_sizes, int n_in,
                              void* d_out, int out_size, void* d_ws, size_t ws_size,
                              hipStream_t stream) {
    const float* x    = (const float*)d_in[0];
    const float* Wih0 = (const float*)d_in[1];
    const float* Whh0 = (const float*)d_in[2];
    const float* bih0 = (const float*)d_in[3];
    const float* bhh0 = (const float*)d_in[4];
    const float* Wih1 = (const float*)d_in[5];
    const float* Whh1 = (const float*)d_in[6];
    const float* bih1 = (const float*)d_in[7];
    const float* bhh1 = (const float*)d_in[8];
    const float* fcW  = (const float*)d_in[9];
    const float* fcb  = (const float*)d_in[10];

    char* ws = (char*)d_ws;
    half_t* h1buf  = (half_t*)(ws + OFF_H1);
    half_t* h2buf  = (half_t*)(ws + OFF_H2);
    float*  c1     = (float*)(ws + OFF_C1);
    float*  c2     = (float*)(ws + OFF_C2);
    float*  opart  = (float*)(ws + OFF_OP);
    float*  bias0  = (float*)(ws + OFF_BIAS0);
    float*  bias1  = (float*)(ws + OFF_BIAS1);
    half_t* x_h    = (half_t*)(ws + OFF_XH);
    half_t* wih0_h = (half_t*)(ws + OFF_WIH0);
    half_t* whh0_h = (half_t*)(ws + OFF_WHH0);
    half_t* wih1_h = (half_t*)(ws + OFF_WIH1);
    half_t* whh1_h = (half_t*)(ws + OFF_WHH1);

    // zero states + FC partials (ws is poisoned 0xAA before every launch)
    hipMemsetAsync(d_ws, 0, ZBYTES, stream);

    k_bias<<<dim3((G_ + 255) / 256), dim3(256), 0, stream>>>(bih0, bhh0, bih1, bhh1, bias0, bias1);
    k_cvt<<<dim3(2048), dim3(256), 0, stream>>>(x,    x_h,    B_ * S_ * F_);
    k_cvt<<<dim3(256),  dim3(256), 0, stream>>>(Wih0, wih0_h, G_ * F_);
    k_cvt<<<dim3(2048), dim3(256), 0, stream>>>(Whh0, whh0_h, G_ * H_);
    k_cvt<<<dim3(2048), dim3(256), 0, stream>>>(Whh1, whh0_h ? wih1_h : wih1_h, G_ * H_); // placeholder avoided below
    // (relaunch correctly — keep explicit, the line above converts Whh1 into wih1_h slot by mistake otherwise)

    // NOTE: explicit correct conversions:
    k_cvt<<<dim3(2048), dim3(256), 0, stream>>>(Wih1, wih1_h, G_ * H_);
    k_cvt<<<dim3(2048), dim3(256), 0, stream>>>(Whh1, whh1_h, G_ * H_);

    dim3 grid(512), blk(256);
    for (int t = 0; t <= S_; ++t) {
        k_phase<<<grid, blk, 0, stream>>>(t, x_h,
                                          wih0_h, whh0_h, bias0, c1, h1buf,
                                          wih1_h, whh1_h, bias1, c2, h2buf,
                                          fcW, opart);
    }
    k_final<<<dim3((B_ * O_ + 255) / 256), dim3(256), 0, stream>>>(opart, fcb, (float*)d_out);
}